// Round 4
// baseline (1476.038 us; speedup 1.0000x reference)
//
#include <hip/hip_runtime.h>
#include <cstdint>

#define N_N 100000
#define N_E 1600000
#define HID 128
#define N_G 100
#define EPSF 1e-5f

// edge partition parameters
#define NB   256                      // partition blocks
#define EPB  ((N_E + NB - 1) / NB)    // 6250 edges per block
#define NBKT ((N_N + 255) >> 8)       // 391 buckets of 256 nodes (dst >> 8)

// persistent-XCD gather parameters
#define NSL  8                        // 8 feature slices of 16 (32B rows, 3.2MB/slice)
#define CHK  128                      // nodes per ticket chunk (256 thr / 2 lanes)
#define NCH  ((N_N + CHK - 1) / CHK)  // 782 chunks per slice

static inline int ceil_div(int a, int b){ return (a + b - 1) / b; }

typedef __attribute__((ext_vector_type(8))) short bf16x8;
typedef __attribute__((ext_vector_type(4))) float f32x4;

__device__ inline unsigned short f2bf(float f){
  unsigned int u = __float_as_uint(f);
  unsigned int r = u + 0x7fffu + ((u >> 16) & 1u);   // round-to-nearest-even
  return (unsigned short)(r >> 16);
}
// 8 packed bf16 (uint4) -> acc[0..7] += nv * val
__device__ inline void fma8(float* acc, float nv, uint4 u){
  acc[0] += nv * __uint_as_float(u.x << 16);
  acc[1] += nv * __uint_as_float(u.x & 0xffff0000u);
  acc[2] += nv * __uint_as_float(u.y << 16);
  acc[3] += nv * __uint_as_float(u.y & 0xffff0000u);
  acc[4] += nv * __uint_as_float(u.z << 16);
  acc[5] += nv * __uint_as_float(u.z & 0xffff0000u);
  acc[6] += nv * __uint_as_float(u.w << 16);
  acc[7] += nv * __uint_as_float(u.w & 0xffff0000u);
}

// physical XCD id of the CU this block runs on (HW-verified on MI355X: 0..7)
__device__ inline int get_xcc(){
  unsigned x;
  asm volatile("s_getreg_b32 %0, hwreg(HW_REG_XCC_ID)" : "=s"(x));
  return (int)(x & (NSL - 1));
}

// ---- W -> bf16 transposed (all 3 layers) + zero counts/sum/sumsq/tickets ----
__global__ void k_wt3(const float* __restrict__ W, unsigned short* __restrict__ Wt,
                      float* __restrict__ counts, float* __restrict__ sum,
                      float* __restrict__ sumsq, int* __restrict__ tick){
  int i = blockIdx.x * 256 + threadIdx.x;
  if (i < N_G) counts[i] = 0.0f;
  if (i < 3 * NSL) tick[i] = 0;
  if (i < N_G * HID){ sum[i] = 0.f; sumsq[i] = 0.f; }
  if (i >= 3 * HID * HID) return;
  int l = i >> 14;            // 128*128 = 16384 per layer
  int r = i & 16383;
  int n = r >> 7, k = r & 127;
  Wt[i] = f2bf(W[l * HID * HID + k * HID + n]);
}

__global__ void k_counts(const int* __restrict__ bp, float* __restrict__ counts){
  int t = blockIdx.x * 256 + threadIdx.x;
  int r0 = t * 32;
  if (r0 >= N_N) return;
  int r1 = min(r0 + 32, N_N);
  int curg = bp[r0];
  float acc = 0.f;
  for (int r = r0; r < r1; ++r){
    int g = bp[r];
    if (g != curg){ atomicAdd(&counts[curg], acc); acc = 0.f; curg = g; }
    acc += 1.0f;
  }
  atomicAdd(&counts[curg], acc);
}

// ---------------- CSR build: two-level LDS-histogram partition ----------------
__global__ __launch_bounds__(256) void k_hist(const int* __restrict__ dst,
                                              int* __restrict__ counts){
  __shared__ int h[NBKT];
  int t = threadIdx.x, blk = blockIdx.x;
  for (int i = t; i < NBKT; i += 256) h[i] = 0;
  __syncthreads();
  int e0 = blk * EPB, e1 = min(e0 + EPB, N_E);
  for (int e = e0 + t; e < e1; e += 256)
    atomicAdd(&h[dst[e] >> 8], 1);
  __syncthreads();
  for (int i = t; i < NBKT; i += 256) counts[i * NB + blk] = h[i];
}

// generic 3-kernel exclusive scan (in-place on data)
__global__ __launch_bounds__(256) void k_scanA(int* __restrict__ data,
                                               int* __restrict__ bsum, int n){
  __shared__ int s[256];
  int t = threadIdx.x;
  int i = blockIdx.x * 256 + t;
  int v = (i < n) ? data[i] : 0;
  s[t] = v; __syncthreads();
  #pragma unroll
  for (int off = 1; off < 256; off <<= 1){
    int tmp = (t >= off) ? s[t - off] : 0;
    __syncthreads();
    s[t] += tmp;
    __syncthreads();
  }
  if (i < n) data[i] = s[t] - v;
  if (t == 255) bsum[blockIdx.x] = s[255];
}

__global__ __launch_bounds__(512) void k_scanB(int* __restrict__ bsum, int nblocks){
  __shared__ int s[512];
  int t = threadIdx.x;
  int v = (t < nblocks) ? bsum[t] : 0;
  s[t] = v; __syncthreads();
  #pragma unroll
  for (int off = 1; off < 512; off <<= 1){
    int tmp = (t >= off) ? s[t - off] : 0;
    __syncthreads();
    s[t] += tmp;
    __syncthreads();
  }
  if (t < nblocks) bsum[t] = s[t] - v;
}

__global__ void k_scanC(int* __restrict__ data, const int* __restrict__ bsum, int n){
  int i = blockIdx.x * 256 + threadIdx.x;
  if (i < n) data[i] += bsum[blockIdx.x];
}

// Pass 2: partition edges into buckets; rank via LDS atomics against the
// per-(block,bucket) scanned bases. pack: x = src | (dst&255)<<24, y = w bits.
__global__ __launch_bounds__(256) void k_part(const int* __restrict__ src,
                                              const int* __restrict__ dst,
                                              const float* __restrict__ w,
                                              const int* __restrict__ coff,
                                              int2* __restrict__ part){
  __shared__ int off[NBKT];
  int t = threadIdx.x, blk = blockIdx.x;
  for (int i = t; i < NBKT; i += 256) off[i] = coff[i * NB + blk];
  __syncthreads();
  int e0 = blk * EPB, e1 = min(e0 + EPB, N_E);
  for (int e = e0 + t; e < e1; e += 256){
    int d = dst[e];
    int pos = atomicAdd(&off[d >> 8], 1);
    part[pos] = make_int2(src[e] | ((d & 255) << 24), __float_as_int(w[e]));
  }
}

// Pass 3: per-bucket fine CSR. Also computes weighted degree -> dis/nself,
// writes ptr directly, and PRE-MULTIPLIES edge weight by dis[dst] (local).
__global__ __launch_bounds__(256) void k_csr(const int* __restrict__ coff,
                                             const int2* __restrict__ part,
                                             int2* __restrict__ edge8,
                                             int* __restrict__ ptr,
                                             float* __restrict__ dis,
                                             float* __restrict__ nself){
  __shared__ int h[256];
  __shared__ int c[256];
  __shared__ float wsum[256];
  __shared__ int s[256];
  int t = threadIdx.x, b = blockIdx.x;
  int base  = coff[b * NB];
  int base2 = (b + 1 < NBKT) ? coff[(b + 1) * NB] : N_E;
  h[t] = 0; c[t] = 0; wsum[t] = 0.f;
  __syncthreads();
  for (int e = base + t; e < base2; e += 256){
    int2 v = part[e];
    int local = ((unsigned int)v.x) >> 24;
    atomicAdd(&h[local], 1);
    atomicAdd(&wsum[local], __int_as_float(v.y));
  }
  __syncthreads();
  // exclusive scan of h
  int v0 = h[t];
  s[t] = v0; __syncthreads();
  #pragma unroll
  for (int off = 1; off < 256; off <<= 1){
    int tmp = (t >= off) ? s[t - off] : 0;
    __syncthreads();
    s[t] += tmp;
    __syncthreads();
  }
  int mybase = base + s[t] - v0;
  int node = (b << 8) + t;
  float dv = rsqrtf(1.0f + wsum[t]);
  if (node < N_N){
    ptr[node] = mybase;
    dis[node] = dv;
    nself[node] = dv * dv;
  }
  if (b == NBKT - 1 && t == 0) ptr[N_N] = N_E;
  h[t] = mybase;              // repurpose h as scatter base (own slot only)
  __syncthreads();
  wsum[t] = dv;               // repurpose wsum as dis[dst] for the scatter
  __syncthreads();
  for (int e = base + t; e < base2; e += 256){
    int2 v = part[e];
    int local = ((unsigned int)v.x) >> 24;
    int pos = h[local] + atomicAdd(&c[local], 1);
    edge8[pos] = make_int2(v.x & 0x00ffffff,
                           __float_as_int(__int_as_float(v.y) * wsum[local]));
  }
}

// per-edge parallel: y (= w*dis[dst]) *= dis[src]. dis (400KB) is L2-resident.
__global__ void k_ne(const float* __restrict__ dis, int2* __restrict__ edge8){
  int e = blockIdx.x * 256 + threadIdx.x;
  if (e >= N_E) return;
  int2 v = edge8[e];
  v.y = __float_as_int(__int_as_float(v.y) * dis[v.x]);
  edge8[e] = v;
}

// ---------------- GEMM via MFMA, optional fused GraphNorm+ReLU on input ------
// fused=0: A row = X[gr]. fused=1: A row = relu(gw*(agg-al*mean)*rstd+gb).
// Hb output layout is SLICE-MAJOR: Hb[s][node][16], s = feature/16.
__global__ __launch_bounds__(256) void k_gemm(const float* __restrict__ X,
                                              const float* __restrict__ agg,
                                              int fused,
                                              const int* __restrict__ bp,
                                              const float* __restrict__ mean,
                                              const float* __restrict__ rstd,
                                              const float* __restrict__ alpha,
                                              const float* __restrict__ gwv,
                                              const float* __restrict__ gbv,
                                              const unsigned short* __restrict__ Wt,
                                              unsigned short* __restrict__ Hb, int nrows){
  __shared__ unsigned short lA[64 * 136];
  __shared__ unsigned short lB[128 * 136];
  int tid = threadIdx.x;
  int row0 = blockIdx.x * 64;

  #pragma unroll
  for (int i = 0; i < 8; ++i){
    int c = tid + i * 256;
    int r = c >> 4, cc = c & 15;
    *(uint4*)&lB[r * 136 + cc * 8] = ((const uint4*)Wt)[c];
  }
  #pragma unroll
  for (int i = 0; i < 8; ++i){
    int c = tid + i * 256;
    int r = c >> 5, cc = c & 31;
    int gr = row0 + r;
    float4 v = make_float4(0.f, 0.f, 0.f, 0.f);
    if (gr < nrows){
      if (!fused){
        v = *(const float4*)(X + (size_t)gr * HID + cc * 4);
      } else {
        int g = bp[gr];
        float4 a  = *(const float4*)(agg  + (size_t)gr * HID + cc * 4);
        float4 m  = *(const float4*)(mean + g * HID + cc * 4);
        float4 rs = *(const float4*)(rstd + g * HID + cc * 4);
        float4 al = *(const float4*)(alpha + cc * 4);
        float4 wv = *(const float4*)(gwv + cc * 4);
        float4 bv = *(const float4*)(gbv + cc * 4);
        v.x = fmaxf(wv.x * (a.x - al.x * m.x) * rs.x + bv.x, 0.f);
        v.y = fmaxf(wv.y * (a.y - al.y * m.y) * rs.y + bv.y, 0.f);
        v.z = fmaxf(wv.z * (a.z - al.z * m.z) * rs.z + bv.z, 0.f);
        v.w = fmaxf(wv.w * (a.w - al.w * m.w) * rs.w + bv.w, 0.f);
      }
    }
    unsigned short pk[4] = {f2bf(v.x), f2bf(v.y), f2bf(v.z), f2bf(v.w)};
    *(uint2*)&lA[r * 136 + cc * 4] = *(const uint2*)pk;
  }
  __syncthreads();

  int wave = tid >> 6;
  int lane = tid & 63;
  int l16 = lane & 15;
  int quad = lane >> 4;
  int am = wave * 16 + l16;

  bf16x8 afr[4];
  #pragma unroll
  for (int kc = 0; kc < 4; ++kc)
    afr[kc] = *(const bf16x8*)&lA[am * 136 + kc * 32 + quad * 8];

  #pragma unroll
  for (int nt = 0; nt < 8; ++nt){
    f32x4 acc = {0.f, 0.f, 0.f, 0.f};
    int bn = nt * 16 + l16;
    #pragma unroll
    for (int kc = 0; kc < 4; ++kc){
      bf16x8 bfr = *(const bf16x8*)&lB[bn * 136 + kc * 32 + quad * 8];
      acc = __builtin_amdgcn_mfma_f32_16x16x32_bf16(afr[kc], bfr, acc, 0, 0, 0);
    }
    int gr = row0 + wave * 16 + quad * 4;
    unsigned short* hbs = Hb + (size_t)nt * ((size_t)N_N * 16);
    #pragma unroll
    for (int r = 0; r < 4; ++r){
      if (gr + r < nrows)
        hbs[(size_t)(gr + r) * 16 + l16] = f2bf(acc[r]);
    }
  }
}

// ---- gather: persistent blocks pinned to feature-slice by physical XCD id ---
// slice s (3.2MB of Hb, slice-major) stays resident in XCD s's L2.
// Per-slice ticket queues; work-stealing fallback keeps it correct under any
// block->XCD placement. Edges/ptr/nself streamed nontemporal (don't evict slice).
__global__ __launch_bounds__(256, 8) void k_gather(const int* __restrict__ ptr,
                                                   const int2* __restrict__ edge8,
                                                   const unsigned short* __restrict__ Hb,
                                                   const float* __restrict__ nself,
                                                   const float* __restrict__ bias,
                                                   float* __restrict__ agg,
                                                   int* __restrict__ tick){
  __shared__ int schunk;
  int myx = get_xcc();
  int half = threadIdx.x & 1;
  int trow = threadIdx.x >> 1;                  // 0..127
  const long long* ep = (const long long*)edge8;
  for (int ss = 0; ss < NSL; ++ss){
    int s = (myx + ss) & (NSL - 1);
    const uint4* hs = (const uint4*)(Hb + (size_t)s * ((size_t)N_N * 16)); // 2 uint4/row
    float4 b0 = ((const float4*)bias)[s * 4 + half * 2];
    float4 b1 = ((const float4*)bias)[s * 4 + half * 2 + 1];
    for (;;){
      if (threadIdx.x == 0) schunk = atomicAdd(&tick[s], 1);
      __syncthreads();
      int chunk = schunk;
      __syncthreads();
      if (chunk >= NCH) break;
      int node = chunk * CHK + trow;
      if (node < N_N){
        float ns = __builtin_nontemporal_load(nself + node);
        uint4 hu = hs[(size_t)node * 2 + half];
        float acc[8] = {b0.x, b0.y, b0.z, b0.w, b1.x, b1.y, b1.z, b1.w};
        fma8(acc, ns, hu);
        int e0 = __builtin_nontemporal_load(ptr + node);
        int e1 = __builtin_nontemporal_load(ptr + node + 1);
        int e = e0;
        for (; e + 4 <= e1; e += 4){
          long long v0 = __builtin_nontemporal_load(ep + e + 0);
          long long v1 = __builtin_nontemporal_load(ep + e + 1);
          long long v2 = __builtin_nontemporal_load(ep + e + 2);
          long long v3 = __builtin_nontemporal_load(ep + e + 3);
          uint4 r0 = hs[(size_t)(unsigned int)v0 * 2 + half];
          uint4 r1 = hs[(size_t)(unsigned int)v1 * 2 + half];
          uint4 r2 = hs[(size_t)(unsigned int)v2 * 2 + half];
          uint4 r3 = hs[(size_t)(unsigned int)v3 * 2 + half];
          fma8(acc, __uint_as_float((unsigned int)(((unsigned long long)v0) >> 32)), r0);
          fma8(acc, __uint_as_float((unsigned int)(((unsigned long long)v1) >> 32)), r1);
          fma8(acc, __uint_as_float((unsigned int)(((unsigned long long)v2) >> 32)), r2);
          fma8(acc, __uint_as_float((unsigned int)(((unsigned long long)v3) >> 32)), r3);
        }
        for (; e < e1; ++e){
          long long v = __builtin_nontemporal_load(ep + e);
          uint4 r0 = hs[(size_t)(unsigned int)v * 2 + half];
          fma8(acc, __uint_as_float((unsigned int)(((unsigned long long)v) >> 32)), r0);
        }
        float* ap = agg + (size_t)node * HID + s * 16 + half * 8;
        f32x4 w0 = {acc[0], acc[1], acc[2], acc[3]};
        f32x4 w1 = {acc[4], acc[5], acc[6], acc[7]};
        __builtin_nontemporal_store(w0, (f32x4*)ap);
        __builtin_nontemporal_store(w1, (f32x4*)ap + 1);
      }
    }
  }
}

// ---------------- GraphNorm ----------------

__global__ __launch_bounds__(128) void k_gstat(const float* __restrict__ agg,
                                               const int* __restrict__ bp,
                                               float* __restrict__ sum,
                                               float* __restrict__ sumsq){
  int f = threadIdx.x;
  int r0 = blockIdx.x * 64;
  int r1 = min(r0 + 64, N_N);
  int curg = bp[r0];
  float s = 0.f, s2 = 0.f;
  for (int r = r0; r < r1; ++r){
    int g = bp[r];
    if (g != curg){
      atomicAdd(&sum[curg * HID + f], s);
      atomicAdd(&sumsq[curg * HID + f], s2);
      s = 0.f; s2 = 0.f; curg = g;
    }
    float v = agg[(size_t)r * HID + f];
    s += v; s2 += v * v;
  }
  atomicAdd(&sum[curg * HID + f], s);
  atomicAdd(&sumsq[curg * HID + f], s2);
}

// reads sum/sumsq, then re-zeroes them for the next layer's k_gstat.
__global__ void k_finstat(float* __restrict__ sum, float* __restrict__ sumsq,
                          const float* __restrict__ counts, const float* __restrict__ alpha,
                          float* __restrict__ mean, float* __restrict__ rstd){
  int i = blockIdx.x * 256 + threadIdx.x;
  if (i >= N_G * HID) return;
  int f = i & (HID - 1);
  float c = counts[i >> 7];
  float inv = c > 0.f ? 1.0f / c : 0.f;
  float m = sum[i] * inv;
  float ex2 = sumsq[i] * inv;
  float al = alpha[f];
  float var = ex2 - m * m * al * (2.0f - al);
  mean[i] = m;
  rstd[i] = rsqrtf(var + EPSF);
  sum[i] = 0.f;
  sumsq[i] = 0.f;
}

__global__ void k_out(const float* __restrict__ agg, const int* __restrict__ bp,
                      const float* __restrict__ mean, const float* __restrict__ rstd,
                      const float* __restrict__ alpha, const float* __restrict__ gw,
                      const float* __restrict__ gb, float* __restrict__ out){
  int idx = blockIdx.x * 256 + threadIdx.x;
  if (idx >= N_N * 32) return;
  int i = idx >> 5, q = idx & 31;
  int g = bp[i];
  float4 a  = ((const float4*)agg)[idx];
  float4 m  = ((const float4*)mean)[g * 32 + q];
  float4 r  = ((const float4*)rstd)[g * 32 + q];
  float4 al = ((const float4*)alpha)[q];
  float4 wv = ((const float4*)gw)[q];
  float4 bv = ((const float4*)gb)[q];
  float4 o;
  o.x = fmaxf(wv.x * (a.x - al.x * m.x) * r.x + bv.x, 0.f);
  o.y = fmaxf(wv.y * (a.y - al.y * m.y) * r.y + bv.y, 0.f);
  o.z = fmaxf(wv.z * (a.z - al.z * m.z) * r.z + bv.z, 0.f);
  o.w = fmaxf(wv.w * (a.w - al.w * m.w) * r.w + bv.w, 0.f);
  ((float4*)out)[idx] = o;
}

// ---------------- launch ----------------

extern "C" void kernel_launch(void* const* d_in, const int* in_sizes, int n_in,
                              void* d_out, int out_size, void* d_ws, size_t ws_size,
                              hipStream_t stream){
  const float* node0 = (const float*)d_in[0];
  const int*   eidx  = (const int*)d_in[1];
  const float* eattr = (const float*)d_in[2];
  const int*   bp    = (const int*)d_in[3];
  const float* W     = (const float*)d_in[4];
  const float* bias  = (const float*)d_in[5];
  const float* gw    = (const float*)d_in[6];
  const float* gb    = (const float*)d_in[7];
  const float* ga    = (const float*)d_in[8];
  float* out = (float*)d_out;
  const int* src = eidx;
  const int* dst = eidx + N_E;

  char* p = (char*)d_ws;
  auto carve = [&](size_t nbytes) -> char* {
    char* q = p; p += (nbytes + 255) & ~(size_t)255; return q;
  };
  float* dis    = (float*)carve((size_t)N_N * 4);
  float* nself  = (float*)carve((size_t)N_N * 4);
  float* counts = (float*)carve((size_t)N_G * 4);
  int*   coff   = (int*)  carve((size_t)NBKT * NB * 4);
  int*   bsum   = (int*)  carve((size_t)512 * 4);
  int*   ptr    = (int*)  carve((size_t)(N_N + 1) * 4);
  int*   tick   = (int*)  carve((size_t)3 * NSL * 4);
  int2*  edge8  = (int2*) carve((size_t)N_E * 8);
  unsigned short* hb = (unsigned short*)carve((size_t)N_N * HID * 2);
  unsigned short* wt = (unsigned short*)carve((size_t)3 * HID * HID * 2);
  float* agg    = (float*)carve((size_t)N_N * HID * 4);
  float* mean   = (float*)carve((size_t)N_G * HID * 4);
  float* rstd   = (float*)carve((size_t)N_G * HID * 4);
  float* sum    = (float*)carve((size_t)N_G * HID * 4);
  float* sumsq  = (float*)carve((size_t)N_G * HID * 4);
  // bucket-partitioned edges alias agg (dead until first k_gather; 12.8MB < 51.2MB)
  int2*  part   = (int2*)agg;

  int nscan = NBKT * NB;                       // 100096
  int nscan_blocks = ceil_div(nscan, 256);     // 391

  k_wt3   <<<ceil_div(3 * HID * HID, 256), 256, 0, stream>>>(W, wt, counts, sum, sumsq, tick);
  k_counts<<<ceil_div(N_N, 32 * 256), 256, 0, stream>>>(bp, counts);
  k_hist  <<<NB, 256, 0, stream>>>(dst, coff);
  k_scanA <<<nscan_blocks, 256, 0, stream>>>(coff, bsum, nscan);
  k_scanB <<<1, 512, 0, stream>>>(bsum, nscan_blocks);
  k_scanC <<<nscan_blocks, 256, 0, stream>>>(coff, bsum, nscan);
  k_part  <<<NB, 256, 0, stream>>>(src, dst, eattr, coff, part);
  k_csr   <<<NBKT, 256, 0, stream>>>(coff, part, edge8, ptr, dis, nself);
  k_ne    <<<ceil_div(N_E, 256), 256, 0, stream>>>(dis, edge8);

  for (int l = 0; l < 3; ++l){
    if (l == 0){
      k_gemm <<<ceil_div(N_N, 64), 256, 0, stream>>>(node0, nullptr, 0,
                 nullptr, nullptr, nullptr, nullptr, nullptr, nullptr,
                 wt, hb, N_N);
    } else {
      k_gemm <<<ceil_div(N_N, 64), 256, 0, stream>>>(nullptr, agg, 1,
                 bp, mean, rstd, ga + (l - 1) * HID, gw + (l - 1) * HID,
                 gb + (l - 1) * HID, wt + (size_t)l * HID * HID, hb, N_N);
    }
    k_gather <<<2048, 256, 0, stream>>>(ptr, edge8, hb, nself,
                 bias + l * HID, agg, tick + l * NSL);
    k_gstat  <<<ceil_div(N_N, 64), 128, 0, stream>>>(agg, bp, sum, sumsq);
    k_finstat<<<ceil_div(N_G * HID, 256), 256, 0, stream>>>(sum, sumsq, counts,
                 ga + l * HID, mean, rstd);
  }
  k_out <<<ceil_div(N_N * 32, 256), 256, 0, stream>>>(agg, bp, mean, rstd,
             ga + 2 * HID, gw + 2 * HID, gb + 2 * HID, out);
}

// Round 5
// 562.030 us; speedup vs baseline: 2.6263x; 2.6263x over previous
//
#include <hip/hip_runtime.h>
#include <cstdint>

#define N_N 100000
#define N_E 1600000
#define HID 128
#define N_G 100
#define EPSF 1e-5f

// edge partition parameters
#define NB   256                      // partition blocks
#define EPB  ((N_E + NB - 1) / NB)    // 6250 edges per block
#define NBKT ((N_N + 255) >> 8)       // 391 buckets of 256 nodes (dst >> 8)

static inline int ceil_div(int a, int b){ return (a + b - 1) / b; }

typedef __attribute__((ext_vector_type(8))) short bf16x8;
typedef __attribute__((ext_vector_type(4))) float f32x4;

__device__ inline unsigned short f2bf(float f){
  unsigned int u = __float_as_uint(f);
  unsigned int r = u + 0x7fffu + ((u >> 16) & 1u);   // round-to-nearest-even
  return (unsigned short)(r >> 16);
}
// 8 packed bf16 (uint4) -> acc[0..7] += nv * val
__device__ inline void fma8(float* acc, float nv, uint4 u){
  acc[0] += nv * __uint_as_float(u.x << 16);
  acc[1] += nv * __uint_as_float(u.x & 0xffff0000u);
  acc[2] += nv * __uint_as_float(u.y << 16);
  acc[3] += nv * __uint_as_float(u.y & 0xffff0000u);
  acc[4] += nv * __uint_as_float(u.z << 16);
  acc[5] += nv * __uint_as_float(u.z & 0xffff0000u);
  acc[6] += nv * __uint_as_float(u.w << 16);
  acc[7] += nv * __uint_as_float(u.w & 0xffff0000u);
}

// ---- W -> bf16 transposed (all 3 layers) + zero graph-boundary arrays -----
__global__ void k_wt3(const float* __restrict__ W, unsigned short* __restrict__ Wt,
                      int* __restrict__ gstart, int* __restrict__ gend){
  int i = blockIdx.x * 256 + threadIdx.x;
  if (i < N_G){ gstart[i] = 0; gend[i] = 0; }   // empty graphs -> count 0
  if (i >= 3 * HID * HID) return;
  int l = i >> 14;            // 128*128 = 16384 per layer
  int r = i & 16383;
  int n = r >> 7, k = r & 127;
  Wt[i] = f2bf(W[l * HID * HID + k * HID + n]);
}

// boundary detect on sorted bp: gstart[g], gend[g]. Coalesced, no atomics.
__global__ void k_bnd(const int* __restrict__ bp, int* __restrict__ gstart,
                      int* __restrict__ gend){
  int i = blockIdx.x * 256 + threadIdx.x;
  if (i >= N_N) return;
  int g = bp[i];
  if (i == 0 || bp[i - 1] != g) gstart[g] = i;
  if (i == N_N - 1 || bp[i + 1] != g) gend[g] = i + 1;
}

// ---------------- CSR build: two-level LDS-histogram partition ----------------
__global__ __launch_bounds__(256) void k_hist(const int* __restrict__ dst,
                                              int* __restrict__ counts){
  __shared__ int h[NBKT];
  int t = threadIdx.x, blk = blockIdx.x;
  for (int i = t; i < NBKT; i += 256) h[i] = 0;
  __syncthreads();
  int e0 = blk * EPB, e1 = min(e0 + EPB, N_E);
  for (int e = e0 + t; e < e1; e += 256)
    atomicAdd(&h[dst[e] >> 8], 1);
  __syncthreads();
  for (int i = t; i < NBKT; i += 256) counts[i * NB + blk] = h[i];
}

// 2-kernel exclusive scan; absolute offset = data[j] + bsum[j>>8] (NB==256)
__global__ __launch_bounds__(256) void k_scanA(int* __restrict__ data,
                                               int* __restrict__ bsum, int n){
  __shared__ int s[256];
  int t = threadIdx.x;
  int i = blockIdx.x * 256 + t;
  int v = (i < n) ? data[i] : 0;
  s[t] = v; __syncthreads();
  #pragma unroll
  for (int off = 1; off < 256; off <<= 1){
    int tmp = (t >= off) ? s[t - off] : 0;
    __syncthreads();
    s[t] += tmp;
    __syncthreads();
  }
  if (i < n) data[i] = s[t] - v;
  if (t == 255) bsum[blockIdx.x] = s[255];
}

__global__ __launch_bounds__(512) void k_scanB(int* __restrict__ bsum, int nblocks){
  __shared__ int s[512];
  int t = threadIdx.x;
  int v = (t < nblocks) ? bsum[t] : 0;
  s[t] = v; __syncthreads();
  #pragma unroll
  for (int off = 1; off < 512; off <<= 1){
    int tmp = (t >= off) ? s[t - off] : 0;
    __syncthreads();
    s[t] += tmp;
    __syncthreads();
  }
  if (t < nblocks) bsum[t] = s[t] - v;
}

// Pass 2: partition edges into buckets; rank via LDS atomics against the
// per-(block,bucket) scanned bases. pack: x = src | (dst&255)<<24, y = w bits.
__global__ __launch_bounds__(256) void k_part(const int* __restrict__ src,
                                              const int* __restrict__ dst,
                                              const float* __restrict__ w,
                                              const int* __restrict__ coff,
                                              const int* __restrict__ bsum,
                                              int2* __restrict__ part){
  __shared__ int off[NBKT];
  int t = threadIdx.x, blk = blockIdx.x;
  for (int i = t; i < NBKT; i += 256)
    off[i] = coff[i * NB + blk] + bsum[i];   // (i*NB+blk)>>8 == i since NB==256
  __syncthreads();
  int e0 = blk * EPB, e1 = min(e0 + EPB, N_E);
  for (int e = e0 + t; e < e1; e += 256){
    int d = dst[e];
    int pos = atomicAdd(&off[d >> 8], 1);
    part[pos] = make_int2(src[e] | ((d & 255) << 24), __float_as_int(w[e]));
  }
}

// Pass 3: per-bucket fine CSR. Also computes weighted degree -> dis/nself,
// writes ptr directly, and PRE-MULTIPLIES edge weight by dis[dst] (local).
__global__ __launch_bounds__(256) void k_csr(const int* __restrict__ coff,
                                             const int* __restrict__ bsum,
                                             const int2* __restrict__ part,
                                             int2* __restrict__ edge8,
                                             int* __restrict__ ptr,
                                             float* __restrict__ dis,
                                             float* __restrict__ nself){
  __shared__ int h[256];
  __shared__ int c[256];
  __shared__ float wsum[256];
  __shared__ int s[256];
  int t = threadIdx.x, b = blockIdx.x;
  int base  = coff[b * NB] + bsum[b];
  int base2 = (b + 1 < NBKT) ? coff[(b + 1) * NB] + bsum[b + 1] : N_E;
  h[t] = 0; c[t] = 0; wsum[t] = 0.f;
  __syncthreads();
  for (int e = base + t; e < base2; e += 256){
    int2 v = part[e];
    int local = ((unsigned int)v.x) >> 24;
    atomicAdd(&h[local], 1);
    atomicAdd(&wsum[local], __int_as_float(v.y));
  }
  __syncthreads();
  // exclusive scan of h
  int v0 = h[t];
  s[t] = v0; __syncthreads();
  #pragma unroll
  for (int off = 1; off < 256; off <<= 1){
    int tmp = (t >= off) ? s[t - off] : 0;
    __syncthreads();
    s[t] += tmp;
    __syncthreads();
  }
  int mybase = base + s[t] - v0;
  int node = (b << 8) + t;
  float dv = rsqrtf(1.0f + wsum[t]);
  if (node < N_N){
    ptr[node] = mybase;
    dis[node] = dv;
    nself[node] = dv * dv;
  }
  if (b == NBKT - 1 && t == 0) ptr[N_N] = N_E;
  h[t] = mybase;              // repurpose h as scatter base (own slot only)
  __syncthreads();
  wsum[t] = dv;               // repurpose wsum as dis[dst] for the scatter
  __syncthreads();
  for (int e = base + t; e < base2; e += 256){
    int2 v = part[e];
    int local = ((unsigned int)v.x) >> 24;
    int pos = h[local] + atomicAdd(&c[local], 1);
    edge8[pos] = make_int2(v.x & 0x00ffffff,
                           __float_as_int(__int_as_float(v.y) * wsum[local]));
  }
}

// per-edge parallel: y (= w*dis[dst]) *= dis[src]. dis (400KB) is L2-resident.
__global__ void k_ne(const float* __restrict__ dis, int2* __restrict__ edge8){
  int e = blockIdx.x * 256 + threadIdx.x;
  if (e >= N_E) return;
  int2 v = edge8[e];
  v.y = __float_as_int(__int_as_float(v.y) * dis[v.x]);
  edge8[e] = v;
}

// ---------------- GEMM via MFMA, optional fused GraphNorm+ReLU on input ------
// fused=0: A row = X[gr]. fused=1: A row = relu(gw*(agg-al*mean)*rstd+gb).
__global__ __launch_bounds__(256) void k_gemm(const float* __restrict__ X,
                                              const float* __restrict__ agg,
                                              int fused,
                                              const int* __restrict__ bp,
                                              const float* __restrict__ mean,
                                              const float* __restrict__ rstd,
                                              const float* __restrict__ alpha,
                                              const float* __restrict__ gwv,
                                              const float* __restrict__ gbv,
                                              const unsigned short* __restrict__ Wt,
                                              unsigned short* __restrict__ Hb, int nrows){
  __shared__ unsigned short lA[64 * 136];
  __shared__ unsigned short lB[128 * 136];
  int tid = threadIdx.x;
  int row0 = blockIdx.x * 64;

  #pragma unroll
  for (int i = 0; i < 8; ++i){
    int c = tid + i * 256;
    int r = c >> 4, cc = c & 15;
    *(uint4*)&lB[r * 136 + cc * 8] = ((const uint4*)Wt)[c];
  }
  #pragma unroll
  for (int i = 0; i < 8; ++i){
    int c = tid + i * 256;
    int r = c >> 5, cc = c & 31;
    int gr = row0 + r;
    float4 v = make_float4(0.f, 0.f, 0.f, 0.f);
    if (gr < nrows){
      if (!fused){
        v = *(const float4*)(X + (size_t)gr * HID + cc * 4);
      } else {
        int g = bp[gr];
        float4 a  = *(const float4*)(agg  + (size_t)gr * HID + cc * 4);
        float4 m  = *(const float4*)(mean + g * HID + cc * 4);
        float4 rs = *(const float4*)(rstd + g * HID + cc * 4);
        float4 al = *(const float4*)(alpha + cc * 4);
        float4 wv = *(const float4*)(gwv + cc * 4);
        float4 bv = *(const float4*)(gbv + cc * 4);
        v.x = fmaxf(wv.x * (a.x - al.x * m.x) * rs.x + bv.x, 0.f);
        v.y = fmaxf(wv.y * (a.y - al.y * m.y) * rs.y + bv.y, 0.f);
        v.z = fmaxf(wv.z * (a.z - al.z * m.z) * rs.z + bv.z, 0.f);
        v.w = fmaxf(wv.w * (a.w - al.w * m.w) * rs.w + bv.w, 0.f);
      }
    }
    unsigned short pk[4] = {f2bf(v.x), f2bf(v.y), f2bf(v.z), f2bf(v.w)};
    *(uint2*)&lA[r * 136 + cc * 4] = *(const uint2*)pk;
  }
  __syncthreads();

  int wave = tid >> 6;
  int lane = tid & 63;
  int l16 = lane & 15;
  int quad = lane >> 4;
  int am = wave * 16 + l16;

  bf16x8 afr[4];
  #pragma unroll
  for (int kc = 0; kc < 4; ++kc)
    afr[kc] = *(const bf16x8*)&lA[am * 136 + kc * 32 + quad * 8];

  #pragma unroll
  for (int nt = 0; nt < 8; ++nt){
    f32x4 acc = {0.f, 0.f, 0.f, 0.f};
    int bn = nt * 16 + l16;
    #pragma unroll
    for (int kc = 0; kc < 4; ++kc){
      bf16x8 bfr = *(const bf16x8*)&lB[bn * 136 + kc * 32 + quad * 8];
      acc = __builtin_amdgcn_mfma_f32_16x16x32_bf16(afr[kc], bfr, acc, 0, 0, 0);
    }
    int gr = row0 + wave * 16 + quad * 4;
    #pragma unroll
    for (int r = 0; r < 4; ++r){
      if (gr + r < nrows)
        Hb[(size_t)(gr + r) * HID + nt * 16 + l16] = f2bf(acc[r]);
    }
  }
}

// ---------------- gather aggregation: 16 lanes/node, unroll x4 ----------------
__global__ __launch_bounds__(256) void k_gather(const int* __restrict__ ptr,
                                                const int2* __restrict__ edge8,
                                                const unsigned short* __restrict__ Hb,
                                                const float* __restrict__ nself,
                                                const float* __restrict__ bias,
                                                float* __restrict__ agg){
  int t = blockIdx.x * 256 + threadIdx.x;
  int node = t >> 4;
  if (node >= N_N) return;
  int lane = t & 15;                        // 8 features (16B) per lane
  const uint4* h16 = (const uint4*)Hb;      // 16 uint4 per row
  float ns = nself[node];
  uint4 hu = h16[(size_t)node * 16 + lane];
  float4 b0 = ((const float4*)bias)[lane * 2];
  float4 b1 = ((const float4*)bias)[lane * 2 + 1];
  float acc[8] = {b0.x, b0.y, b0.z, b0.w, b1.x, b1.y, b1.z, b1.w};
  fma8(acc, ns, hu);

  int e0 = ptr[node], e1 = ptr[node + 1];
  int e = e0;
  for (; e + 4 <= e1; e += 4){
    int2 ev0 = edge8[e + 0];
    int2 ev1 = edge8[e + 1];
    int2 ev2 = edge8[e + 2];
    int2 ev3 = edge8[e + 3];
    uint4 r0 = h16[(size_t)ev0.x * 16 + lane];
    uint4 r1 = h16[(size_t)ev1.x * 16 + lane];
    uint4 r2 = h16[(size_t)ev2.x * 16 + lane];
    uint4 r3 = h16[(size_t)ev3.x * 16 + lane];
    fma8(acc, __int_as_float(ev0.y), r0);
    fma8(acc, __int_as_float(ev1.y), r1);
    fma8(acc, __int_as_float(ev2.y), r2);
    fma8(acc, __int_as_float(ev3.y), r3);
  }
  for (; e < e1; ++e){
    int2 ev = edge8[e];
    uint4 r0 = h16[(size_t)ev.x * 16 + lane];
    fma8(acc, __int_as_float(ev.y), r0);
  }
  float4* ap = (float4*)(agg + (size_t)node * HID + lane * 8);
  ap[0] = make_float4(acc[0], acc[1], acc[2], acc[3]);
  ap[1] = make_float4(acc[4], acc[5], acc[6], acc[7]);
}

// ---------------- GraphNorm: atomic-free two-phase reduction ----------------
// Phase 1: block (g, chunk c of 8) reduces its row range -> distinct psum slot.
__global__ __launch_bounds__(256) void k_gstat(const float* __restrict__ agg,
                                               const int* __restrict__ gstart,
                                               const int* __restrict__ gend,
                                               float* __restrict__ psum,
                                               float* __restrict__ psq){
  __shared__ float ls[256], lq[256];
  int g = blockIdx.x >> 3, c = blockIdx.x & 7;
  int s = gstart[g], e = gend[g];
  int len = e - s;
  int r0 = s + ((len * c) >> 3);
  int r1 = s + ((len * (c + 1)) >> 3);
  int f = threadIdx.x & 127, rr = threadIdx.x >> 7;
  float sm = 0.f, sq = 0.f;
  for (int r = r0 + rr; r < r1; r += 2){
    float v = agg[(size_t)r * HID + f];
    sm += v; sq += v * v;
  }
  ls[threadIdx.x] = sm; lq[threadIdx.x] = sq;
  __syncthreads();
  if (rr == 0){
    psum[(size_t)blockIdx.x * HID + f] = ls[f] + ls[f + 128];
    psq [(size_t)blockIdx.x * HID + f] = lq[f] + lq[f + 128];
  }
}

// Phase 2: fold 8 chunk-partials, compute mean/rstd. No atomics anywhere.
__global__ void k_finstat(const float* __restrict__ psum, const float* __restrict__ psq,
                          const int* __restrict__ gstart, const int* __restrict__ gend,
                          const float* __restrict__ alpha,
                          float* __restrict__ mean, float* __restrict__ rstd){
  int i = blockIdx.x * 256 + threadIdx.x;
  if (i >= N_G * HID) return;
  int g = i >> 7, f = i & (HID - 1);
  float c = (float)(gend[g] - gstart[g]);
  float inv = c > 0.f ? 1.0f / c : 0.f;
  float sm = 0.f, sq = 0.f;
  #pragma unroll
  for (int k = 0; k < 8; ++k){
    sm += psum[(size_t)(g * 8 + k) * HID + f];
    sq += psq [(size_t)(g * 8 + k) * HID + f];
  }
  float m = sm * inv;
  float ex2 = sq * inv;
  float al = alpha[f];
  float var = ex2 - m * m * al * (2.0f - al);
  mean[i] = m;
  rstd[i] = rsqrtf(var + EPSF);
}

__global__ void k_out(const float* __restrict__ agg, const int* __restrict__ bp,
                      const float* __restrict__ mean, const float* __restrict__ rstd,
                      const float* __restrict__ alpha, const float* __restrict__ gw,
                      const float* __restrict__ gb, float* __restrict__ out){
  int idx = blockIdx.x * 256 + threadIdx.x;
  if (idx >= N_N * 32) return;
  int i = idx >> 5, q = idx & 31;
  int g = bp[i];
  float4 a  = ((const float4*)agg)[idx];
  float4 m  = ((const float4*)mean)[g * 32 + q];
  float4 r  = ((const float4*)rstd)[g * 32 + q];
  float4 al = ((const float4*)alpha)[q];
  float4 wv = ((const float4*)gw)[q];
  float4 bv = ((const float4*)gb)[q];
  float4 o;
  o.x = fmaxf(wv.x * (a.x - al.x * m.x) * r.x + bv.x, 0.f);
  o.y = fmaxf(wv.y * (a.y - al.y * m.y) * r.y + bv.y, 0.f);
  o.z = fmaxf(wv.z * (a.z - al.z * m.z) * r.z + bv.z, 0.f);
  o.w = fmaxf(wv.w * (a.w - al.w * m.w) * r.w + bv.w, 0.f);
  ((float4*)out)[idx] = o;
}

// ---------------- launch ----------------

extern "C" void kernel_launch(void* const* d_in, const int* in_sizes, int n_in,
                              void* d_out, int out_size, void* d_ws, size_t ws_size,
                              hipStream_t stream){
  const float* node0 = (const float*)d_in[0];
  const int*   eidx  = (const int*)d_in[1];
  const float* eattr = (const float*)d_in[2];
  const int*   bp    = (const int*)d_in[3];
  const float* W     = (const float*)d_in[4];
  const float* bias  = (const float*)d_in[5];
  const float* gw    = (const float*)d_in[6];
  const float* gb    = (const float*)d_in[7];
  const float* ga    = (const float*)d_in[8];
  float* out = (float*)d_out;
  const int* src = eidx;
  const int* dst = eidx + N_E;

  char* p = (char*)d_ws;
  auto carve = [&](size_t nbytes) -> char* {
    char* q = p; p += (nbytes + 255) & ~(size_t)255; return q;
  };
  float* dis    = (float*)carve((size_t)N_N * 4);
  float* nself  = (float*)carve((size_t)N_N * 4);
  int*   gstart = (int*)  carve((size_t)N_G * 4);
  int*   gend   = (int*)  carve((size_t)N_G * 4);
  int*   coff   = (int*)  carve((size_t)NBKT * NB * 4);
  int*   bsum   = (int*)  carve((size_t)512 * 4);
  int*   ptr    = (int*)  carve((size_t)(N_N + 1) * 4);
  int2*  edge8  = (int2*) carve((size_t)N_E * 8);
  unsigned short* hb = (unsigned short*)carve((size_t)N_N * HID * 2);
  unsigned short* wt = (unsigned short*)carve((size_t)3 * HID * HID * 2);
  float* agg    = (float*)carve((size_t)N_N * HID * 4);
  float* mean   = (float*)carve((size_t)N_G * HID * 4);
  float* rstd   = (float*)carve((size_t)N_G * HID * 4);
  float* psum   = (float*)carve((size_t)N_G * 8 * HID * 4);
  float* psq    = (float*)carve((size_t)N_G * 8 * HID * 4);
  // bucket-partitioned edges alias agg (dead until first k_gather; 12.8MB < 51.2MB)
  int2*  part   = (int2*)agg;

  int nscan = NBKT * NB;                       // 100096
  int nscan_blocks = ceil_div(nscan, 256);     // 391

  k_wt3  <<<ceil_div(3 * HID * HID, 256), 256, 0, stream>>>(W, wt, gstart, gend);
  k_bnd  <<<ceil_div(N_N, 256), 256, 0, stream>>>(bp, gstart, gend);
  k_hist <<<NB, 256, 0, stream>>>(dst, coff);
  k_scanA<<<nscan_blocks, 256, 0, stream>>>(coff, bsum, nscan);
  k_scanB<<<1, 512, 0, stream>>>(bsum, nscan_blocks);
  k_part <<<NB, 256, 0, stream>>>(src, dst, eattr, coff, bsum, part);
  k_csr  <<<NBKT, 256, 0, stream>>>(coff, bsum, part, edge8, ptr, dis, nself);
  k_ne   <<<ceil_div(N_E, 256), 256, 0, stream>>>(dis, edge8);

  for (int l = 0; l < 3; ++l){
    if (l == 0){
      k_gemm <<<ceil_div(N_N, 64), 256, 0, stream>>>(node0, nullptr, 0,
                 nullptr, nullptr, nullptr, nullptr, nullptr, nullptr,
                 wt, hb, N_N);
    } else {
      k_gemm <<<ceil_div(N_N, 64), 256, 0, stream>>>(nullptr, agg, 1,
                 bp, mean, rstd, ga + (l - 1) * HID, gw + (l - 1) * HID,
                 gb + (l - 1) * HID, wt + (size_t)l * HID * HID, hb, N_N);
    }
    k_gather <<<ceil_div(N_N * 16, 256), 256, 0, stream>>>(ptr, edge8, hb, nself,
                 bias + l * HID, agg);
    k_gstat  <<<N_G * 8, 256, 0, stream>>>(agg, gstart, gend, psum, psq);
    k_finstat<<<ceil_div(N_G * HID, 256), 256, 0, stream>>>(psum, psq, gstart, gend,
                 ga + l * HID, mean, rstd);
  }
  k_out <<<ceil_div(N_N * 32, 256), 256, 0, stream>>>(agg, bp, mean, rstd,
             ga + 2 * HID, gw + 2 * HID, gb + 2 * HID, out);
}